// Round 7
// baseline (208.952 us; speedup 1.0000x reference)
//
#include <hip/hip_runtime.h>

#define H 128
#define CAPC 3072   // per-bucket capacity: mean 2048 + ~22 sigma (128-node buckets)

// ---------------------------------------------------------------------------
// R24 = R23 with the h2b write-out stride bug fixed (was *16, must be *32:
// one h2b/hs row = 128 ushort = 32 uint2; R23's overlap left half of h2b
// poisoned -> absmax 1442). All other R23 content unchanged:
//  1) layer2_fused: 512-thr blocks, 2 nodes per wave, two independent 4-wide
//     pipelined edge streams (halves exposed s1-gather latency).
//  2) fine_scatter: __shfl_up wave scan (1 barrier) instead of 14-barrier
//     Hillis-Steele.
// Accounting (R21/R22): ~90-100us of dur is fixed harness iteration overhead
// (45us ws re-poison fill + reset()'s tiny dispatches); launch boundary cost
// ~3-5us each; controllable kernel interiors ~60us total.
// ---------------------------------------------------------------------------

typedef unsigned long long ull;
using bf16x8 = __attribute__((ext_vector_type(8))) short;
using f32x4  = __attribute__((ext_vector_type(4))) float;

__device__ int g_cursor[512];   // zero at module load; final_kernel re-zeros

__device__ __forceinline__ float bf2f(unsigned short v) {
  return __uint_as_float(((unsigned)v) << 16);
}
__device__ __forceinline__ unsigned short bf16r(float v) {
  unsigned u = __float_as_uint(v);
  u = (u + 0x7FFFu + ((u >> 16) & 1u)) >> 16;   // RNE
  return (unsigned short)u;
}
__device__ __forceinline__ int rfl(int v) {
  return __builtin_amdgcn_readfirstlane(v);
}

// block 0: folded consts; blocks 1..16: transpose W2 -> bf16;
// blocks 17..17+NBATCH-1: bin_scatter chunks (multisplit into 391 buckets).
__global__ __launch_bounds__(1024) void init_bin(
    const int* __restrict__ src, const int* __restrict__ dst,
    const float* __restrict__ ea,
    const float* __restrict__ em_w, const float* __restrict__ em_b,
    const float* __restrict__ l1_w, const float* __restrict__ l1_b,
    const float* __restrict__ l2_w, const float* __restrict__ l2_b,
    const float* __restrict__ n1_b,
    const float* __restrict__ l3_w, const float* __restrict__ l3_b,
    const float* __restrict__ n2w, const float* __restrict__ n3w,
    const float* __restrict__ n3b, const float* __restrict__ dec_w,
    float* __restrict__ consts, unsigned short* __restrict__ w2t,
    ull* __restrict__ spc, int E, int NBUCK) {
  const int bid = blockIdx.x;
  const int tid = threadIdx.x;
  if (bid == 0) {
    // ---- folded consts (k<128 active; all 1024 threads hit barriers) ----
    __shared__ float sa[H], sc[H];
    const int k = tid;
    if (k < H) {
      float u2 = 0.f, c2 = 0.f, u3 = 0.f, c3 = 0.f, vA = 0.f, vB = 0.f;
      for (int j = 0; j < H; ++j) {
        const float ew = em_w[j], eb = em_b[j];
        u2 = fmaf(ew, l2_w[j * H + k], u2);
        c2 = fmaf(eb, l2_w[j * H + k], c2);
        u3 = fmaf(ew, l3_w[j * H + k], u3);
        c3 = fmaf(eb, l3_w[j * H + k], c3);
        vA = fmaf(n3w[k * H + j], dec_w[j], vA);
        vB = fmaf(n3w[k * H + j], dec_w[H + j], vB);
      }
      consts[2 + k]         = u2;
      consts[2 + H + k]     = c2 + l2_b[k] + n1_b[k];
      consts[2 + 2 * H + k] = u3;
      consts[2 + 3 * H + k] = c3 + l3_b[k];
      consts[514 + k]       = vA;
      consts[642 + k]       = vB;
      sa[k] = em_w[k] * l1_w[k];
      sc[k] = em_b[k] * l1_w[k];
    }
    __syncthreads();
    for (int s = 64; s > 0; s >>= 1) {
      if (k < s) { sa[k] += sa[k + s]; sc[k] += sc[k + s]; }
      __syncthreads();
    }
    if (k == 0) { consts[0] = sa[0]; consts[1] = sc[0] + l1_b[0]; }
    __syncthreads();
    if (k < H) {
      sa[k] = n3b[k] * dec_w[k];
      sc[k] = n3b[k] * dec_w[H + k];
    }
    __syncthreads();
    for (int s = 64; s > 0; s >>= 1) {
      if (k < s) { sa[k] += sa[k + s]; sc[k] += sc[k + s]; }
      __syncthreads();
    }
    if (k == 0) { consts[770] = sa[0]; consts[771] = sc[0]; }
    return;
  }
  if (bid <= 16) {
    const int i = (bid - 1) * 1024 + tid;   // 0..16383 exactly
    const int j = i >> 7, k = i & (H - 1);
    w2t[k * H + j] = bf16r(n2w[i]);
    return;
  }
  // ---- bin_scatter chunk (payload u64: hi = src | (dst&127)<<16, lo = ea) --
  __shared__ int lhist[512];
  __shared__ int lbase[512];
  const int base = (bid - 17) * 2048 + tid * 2;
  if (tid < 512) lhist[tid] = 0;
  __syncthreads();
  int s_[2], d_[2], b_[2], r_[2];
  float a_[2];
#pragma unroll
  for (int j = 0; j < 2; ++j) {
    const int e = base + j;
    if (e < E) {
      s_[j] = src[e]; d_[j] = dst[e]; a_[j] = ea[e];
      b_[j] = d_[j] >> 7;
      r_[j] = atomicAdd(&lhist[b_[j]], 1);
    } else {
      b_[j] = -1;
    }
  }
  __syncthreads();
  if (tid < NBUCK && lhist[tid] > 0)
    lbase[tid] = atomicAdd(&g_cursor[tid], lhist[tid]);
  __syncthreads();
#pragma unroll
  for (int j = 0; j < 2; ++j) {
    if (b_[j] >= 0) {
      const int pl = lbase[b_[j]] + r_[j];
      if (pl < CAPC)
        spc[(size_t)b_[j] * CAPC + pl] =
            ((ull)(unsigned)(s_[j] | ((d_[j] & 127) << 16)) << 32) |
            (ull)(unsigned)__float_as_uint(a_[j]);
    }
  }
}

// one block per 128-node bucket: LDS hist + shfl-scan -> permute -> spf
// + rowstart (stride 129); fused layer-1 s1
__global__ __launch_bounds__(1024) void fine_scatter(
    const ull* __restrict__ spc, const float* __restrict__ x,
    const float* __restrict__ consts, int2* __restrict__ spf,
    int* __restrict__ rowstart, float* __restrict__ s1, int N) {
  __shared__ int lh[128];
  __shared__ int sd[128];
  __shared__ int cur[128];
  __shared__ int sdmid;
  __shared__ int2 pay[CAPC];   // 24.5 KB
  const int tid = threadIdx.x;
  const int b = blockIdx.x;
  const int cnt = min(g_cursor[b], CAPC);
  const size_t rbase = (size_t)b * CAPC;
  if (tid < 128) lh[tid] = 0;
  __syncthreads();
  for (int i = tid; i < cnt; i += 1024)
    atomicAdd(&lh[(int)((spc[rbase + i] >> 48) & 127u)], 1);
  __syncthreads();
  // inclusive scan of lh[0..127]: per-wave shfl scan + mid fixup (1 barrier)
  int sv = (tid < 128) ? lh[tid] : 0;
#pragma unroll
  for (int off = 1; off < 64; off <<= 1) {
    const int t = __shfl_up(sv, off, 64);
    if ((tid & 63) >= off) sv += t;
  }
  if (tid == 63) sdmid = sv;
  __syncthreads();
  if (tid < 128) {
    if (tid >= 64) sv += sdmid;
    sd[tid] = sv;
    const int ex = sv - lh[tid];
    cur[tid] = ex;
    rowstart[b * 129 + tid] = (int)rbase + ex;
    if (tid == 0) rowstart[b * 129 + 128] = (int)rbase + cnt;
  }
  __syncthreads();
  for (int i = tid; i < cnt; i += 1024) {
    const ull payv = spc[rbase + i];
    const int dl = (int)((payv >> 48) & 127u);
    const int pos = atomicAdd(&cur[dl], 1);
    pay[pos] = make_int2((int)((payv >> 32) & 0xFFFFu), (int)(unsigned)payv);
  }
  __syncthreads();
  for (int i = tid; i < cnt; i += 1024) spf[rbase + i] = pay[i];
  const int lane = tid & 63, w = tid >> 6;
  const float a1 = consts[0], c1 = consts[1];
  for (int i = w; i < 128; i += 16) {
    const int n = (b << 7) + i;
    if (n >= N) break;
    const int rsl = sd[i] - lh[i], ci = lh[i];
    float part = 0.f;
    for (int j = lane; j < ci; j += 64) {
      const int2 pv = pay[rsl + j];
      part += fmaxf(x[pv.x] + fmaf(a1, __int_as_float(pv.y), c1), 0.f);
    }
#pragma unroll
    for (int o = 32; o >= 1; o >>= 1) part += __shfl_xor(part, o, 64);
    if (lane == 0) s1[n] = x[n] + part;
  }
}

// ---------------- layer 2 fused: edge2 (8 waves x 2 nodes) + MFMA ---------
// Each wave runs TWO independent 4-wide pipelined edge streams (nodes
// 2w and 2w+1, adjacent -> shared rowstart loads). Halves exposed gather
// latency. Per-node group order/accumulators identical to R22.
__global__ __launch_bounds__(512) void layer2_fused(
    const int* __restrict__ rowstart, const int2* __restrict__ sp,
    const float* __restrict__ s1, const float* __restrict__ n1w,
    const float* __restrict__ n1b, const float* __restrict__ consts,
    const unsigned short* __restrict__ w2t, const float* __restrict__ n2b,
    unsigned short* __restrict__ h2b, int N) {
  __shared__ unsigned short t2s[16][136];  // stride 272 B (16-B aligned rows)
  __shared__ unsigned short hs[16][128];   // D staging for coalesced write
  const int tid = threadIdx.x, w = tid >> 6, lane = tid & 63;
  const int node0 = blockIdx.x * 16;
  // phase 1: wave w aggregates nodes node0+2w and node0+2w+1
  {
    const int nA = rfl(node0 + 2 * w);
    const int nB = nA + 1;
    const float w0 = n1w[lane],             w1 = n1w[lane + 64];
    const float u0 = consts[2 + lane],      u1 = consts[2 + lane + 64];
    const float cc0 = consts[2 + H + lane], cc1 = consts[2 + H + lane + 64];
    int rsA = 0, reA = 0, rsB = 0, reB = 0;
    if (nA < N) {
      const int rb = (nA >> 7) * 129 + (nA & 127);
      rsA = rfl(rowstart[rb]);
      reA = rfl(rowstart[rb + 1]);
      if (nB < N) { rsB = reA; reB = rfl(rowstart[rb + 2]); }
    }
    float aA0 = 0.f, aA1 = 0.f, aA2 = 0.f, aA3 = 0.f;
    float aB0 = 0.f, aB1 = 0.f, aB2 = 0.f, aB3 = 0.f;
    auto proc4 = [&](const int2* e, float& p0, float& p1, float& p2,
                     float& p3) {
      const int x0 = rfl(e[0].x), x1 = rfl(e[1].x), x2 = rfl(e[2].x),
                x3 = rfl(e[3].x);
      const float b0 = __int_as_float(rfl(e[0].y));
      const float b1 = __int_as_float(rfl(e[1].y));
      const float b2 = __int_as_float(rfl(e[2].y));
      const float b3 = __int_as_float(rfl(e[3].y));
      const float v0 = s1[x0], v1 = s1[x1], v2 = s1[x2], v3 = s1[x3];
      p0 += fmaxf(fmaf(v0, w0, fmaf(b0, u0, cc0)), 0.f);
      p1 += fmaxf(fmaf(v0, w1, fmaf(b0, u1, cc1)), 0.f);
      p2 += fmaxf(fmaf(v1, w0, fmaf(b1, u0, cc0)), 0.f);
      p3 += fmaxf(fmaf(v1, w1, fmaf(b1, u1, cc1)), 0.f);
      p0 += fmaxf(fmaf(v2, w0, fmaf(b2, u0, cc0)), 0.f);
      p1 += fmaxf(fmaf(v2, w1, fmaf(b2, u1, cc1)), 0.f);
      p2 += fmaxf(fmaf(v3, w0, fmaf(b3, u0, cc0)), 0.f);
      p3 += fmaxf(fmaf(v3, w1, fmaf(b3, u1, cc1)), 0.f);
    };
    int jA = rsA, jB = rsB;
    int2 cA[4], cB[4];
    bool vAg = jA + 4 <= reA;
    bool vBg = jB + 4 <= reB;
    if (vAg) {
#pragma unroll
      for (int u = 0; u < 4; ++u) cA[u] = sp[jA + u];
      jA += 4;
    }
    if (vBg) {
#pragma unroll
      for (int u = 0; u < 4; ++u) cB[u] = sp[jB + u];
      jB += 4;
    }
    while (vAg || vBg) {
      int2 tA[4], tB[4];
      const bool nAv = vAg && (jA + 4 <= reA);
      const bool nBv = vBg && (jB + 4 <= reB);
      if (nAv) {
#pragma unroll
        for (int u = 0; u < 4; ++u) tA[u] = sp[jA + u];
      }
      if (nBv) {
#pragma unroll
        for (int u = 0; u < 4; ++u) tB[u] = sp[jB + u];
      }
      if (vAg) proc4(cA, aA0, aA1, aA2, aA3);
      if (vBg) proc4(cB, aB0, aB1, aB2, aB3);
      if (nAv) {
#pragma unroll
        for (int u = 0; u < 4; ++u) cA[u] = tA[u];
        jA += 4;
      }
      if (nBv) {
#pragma unroll
        for (int u = 0; u < 4; ++u) cB[u] = tB[u];
        jB += 4;
      }
      vAg = nAv;
      vBg = nBv;
    }
    for (; jA < reA; ++jA) {
      const int2 ev = sp[jA];
      const int sx = rfl(ev.x);
      const float av = __int_as_float(rfl(ev.y));
      const float sv = s1[sx];
      aA0 += fmaxf(fmaf(sv, w0, fmaf(av, u0, cc0)), 0.f);
      aA1 += fmaxf(fmaf(sv, w1, fmaf(av, u1, cc1)), 0.f);
    }
    for (; jB < reB; ++jB) {
      const int2 ev = sp[jB];
      const int sx = rfl(ev.x);
      const float av = __int_as_float(rfl(ev.y));
      const float sv = s1[sx];
      aB0 += fmaxf(fmaf(sv, w0, fmaf(av, u0, cc0)), 0.f);
      aB1 += fmaxf(fmaf(sv, w1, fmaf(av, u1, cc1)), 0.f);
    }
    if (nA < N) {
      aA0 += aA2;
      aA1 += aA3;
      const float sn = s1[nA];
      t2s[2 * w][lane]      = bf16r(fmaf(sn, w0, n1b[lane])      + aA0);
      t2s[2 * w][lane + 64] = bf16r(fmaf(sn, w1, n1b[lane + 64]) + aA1);
    } else {
      t2s[2 * w][lane] = 0;
      t2s[2 * w][lane + 64] = 0;
    }
    if (nB < N) {
      aB0 += aB2;
      aB1 += aB3;
      const float sn = s1[nB];
      t2s[2 * w + 1][lane]      = bf16r(fmaf(sn, w0, n1b[lane])      + aB0);
      t2s[2 * w + 1][lane + 64] = bf16r(fmaf(sn, w1, n1b[lane + 64]) + aB1);
    } else {
      t2s[2 * w + 1][lane] = 0;
      t2s[2 * w + 1][lane + 64] = 0;
    }
  }
  __syncthreads();
  // phase 2: all 8 waves each compute a t-slice (16 outputs)
  {
    const int t = w, col = lane & 15, quad = lane >> 4;
    const bf16x8 a0 = *(const bf16x8*)&t2s[col][quad * 8];
    const bf16x8 a1 = *(const bf16x8*)&t2s[col][32 + quad * 8];
    const bf16x8 a2 = *(const bf16x8*)&t2s[col][64 + quad * 8];
    const bf16x8 a3 = *(const bf16x8*)&t2s[col][96 + quad * 8];
    const bf16x8* bcol =
        (const bf16x8*)(w2t + (size_t)(t * 16 + col) * H + quad * 8);
    f32x4 acc = {0.f, 0.f, 0.f, 0.f};
    acc = __builtin_amdgcn_mfma_f32_16x16x32_bf16(a0, bcol[0], acc, 0, 0, 0);
    acc = __builtin_amdgcn_mfma_f32_16x16x32_bf16(a1, bcol[4], acc, 0, 0, 0);
    acc = __builtin_amdgcn_mfma_f32_16x16x32_bf16(a2, bcol[8], acc, 0, 0, 0);
    acc = __builtin_amdgcn_mfma_f32_16x16x32_bf16(a3, bcol[12], acc, 0, 0, 0);
    const float bias = n2b[t * 16 + col];
#pragma unroll
    for (int r = 0; r < 4; ++r)
      hs[quad * 4 + r][t * 16 + col] = bf16r(acc[r] + bias);
  }
  __syncthreads();
  // coalesced write-out: 512 threads = 16 rows x 32 uint2 (one h2b row =
  // 128 ushort = 32 uint2 -- stride MUST be 32; R23's *16 was the bug)
  const int row = tid >> 5, word = tid & 31;
  ((uint2*)h2b)[(size_t)(node0 + row) * 32 + word] =
      ((const uint2*)hs)[row * 32 + word];
}

// ---------------- layer 3: edge agg + collapsed linear decode --------------
// p[n] = t3[n].v3A + cbA, q[n] = t3[n].v3B + cbB  (nn3 is linear!)
// 8-wide software-pipelined (prefetch next group's sp during current
// group's h2b gathers); split accumulators. (R22-verbatim)
__global__ __launch_bounds__(256) void layer3_dot(
    const int* __restrict__ rowstart, const int2* __restrict__ sp,
    const unsigned short* __restrict__ h2b, const float* __restrict__ consts,
    float* __restrict__ p, float* __restrict__ q, int N) {
  const int n = rfl((blockIdx.x * blockDim.x + threadIdx.x) >> 6);
  const int lane = threadIdx.x & 63;
  if (n >= N) return;
  const int k0 = 2 * lane;
  const float u0 = consts[2 + 2 * H + k0], u1 = consts[2 + 2 * H + k0 + 1];
  const float c0 = consts[2 + 3 * H + k0], c1 = consts[2 + 3 * H + k0 + 1];
  const float vA0 = consts[514 + k0], vA1 = consts[514 + k0 + 1];
  const float vB0 = consts[642 + k0], vB1 = consts[642 + k0 + 1];
  const int rb = (n >> 7) * 129 + (n & 127);
  const int rs = rfl(rowstart[rb]), re = rfl(rowstart[rb + 1]);
  float acc0 = 0.f, acc1 = 0.f, acc2 = 0.f, acc3 = 0.f;
  auto proc8 = [&](const int2* cb) {
    int ss[8];
    float aa[8];
    ushort2 hh[8];
#pragma unroll
    for (int u = 0; u < 8; ++u) {
      ss[u] = rfl(cb[u].x);
      aa[u] = __int_as_float(rfl(cb[u].y));
    }
#pragma unroll
    for (int u = 0; u < 8; ++u)
      hh[u] = *(const ushort2*)&h2b[(size_t)ss[u] * H + k0];
#pragma unroll
    for (int u = 0; u < 8; ++u) {
      if (u & 1) {
        acc2 += fmaxf(bf2f(hh[u].x) + fmaf(aa[u], u0, c0), 0.f);
        acc3 += fmaxf(bf2f(hh[u].y) + fmaf(aa[u], u1, c1), 0.f);
      } else {
        acc0 += fmaxf(bf2f(hh[u].x) + fmaf(aa[u], u0, c0), 0.f);
        acc1 += fmaxf(bf2f(hh[u].y) + fmaf(aa[u], u1, c1), 0.f);
      }
    }
  };
  int j = rs;
  if (re - rs >= 8) {
    int2 cb[8];
#pragma unroll
    for (int u = 0; u < 8; ++u) cb[u] = sp[j + u];
    for (j += 8; j + 8 <= re; j += 8) {
      int2 tb[8];
#pragma unroll
      for (int u = 0; u < 8; ++u) tb[u] = sp[j + u];
      proc8(cb);
#pragma unroll
      for (int u = 0; u < 8; ++u) cb[u] = tb[u];
    }
    proc8(cb);
  }
  if (j + 4 <= re) {
    int ss[4];
    float aa[4];
    ushort2 hh[4];
#pragma unroll
    for (int u = 0; u < 4; ++u) {
      const int2 ev = sp[j + u];
      ss[u] = rfl(ev.x);
      aa[u] = __int_as_float(rfl(ev.y));
    }
#pragma unroll
    for (int u = 0; u < 4; ++u)
      hh[u] = *(const ushort2*)&h2b[(size_t)ss[u] * H + k0];
#pragma unroll
    for (int u = 0; u < 4; ++u) {
      acc0 += fmaxf(bf2f(hh[u].x) + fmaf(aa[u], u0, c0), 0.f);
      acc1 += fmaxf(bf2f(hh[u].y) + fmaf(aa[u], u1, c1), 0.f);
    }
    j += 4;
  }
  for (; j < re; ++j) {
    const int2 ev = sp[j];
    const int s0 = rfl(ev.x);
    const float a0 = __int_as_float(rfl(ev.y));
    const ushort2 hv = *(const ushort2*)&h2b[(size_t)s0 * H + k0];
    acc0 += fmaxf(bf2f(hv.x) + fmaf(a0, u0, c0), 0.f);
    acc1 += fmaxf(bf2f(hv.y) + fmaf(a0, u1, c1), 0.f);
  }
  acc0 += acc2;
  acc1 += acc3;
  const ushort2 hn = *(const ushort2*)&h2b[(size_t)n * H + k0];
  const float t0 = bf2f(hn.x) + acc0;
  const float t1 = bf2f(hn.y) + acc1;
  float pd = t0 * vA0 + t1 * vA1;
  float qd = t0 * vB0 + t1 * vB1;
#pragma unroll
  for (int o = 32; o >= 1; o >>= 1) {
    pd += __shfl_xor(pd, o, 64);
    qd += __shfl_xor(qd, o, 64);
  }
  if (lane == 0) {
    p[n] = pd + consts[770];
    q[n] = qd + consts[771];
  }
}

// 2 edges/thread, vectorized index loads; block 0 re-zeros g_cursor for the
// next iteration (runs strictly after bin/fine consumed it this iteration).
__global__ void final_kernel(const int* __restrict__ src,
                             const int* __restrict__ dst,
                             const float* __restrict__ p,
                             const float* __restrict__ q,
                             const float* __restrict__ dec_b,
                             float* __restrict__ out, int E) {
  if (blockIdx.x == 0 && threadIdx.x < 256) {
    g_cursor[threadIdx.x] = 0;
    g_cursor[threadIdx.x + 256] = 0;
  }
  const int e0 = (blockIdx.x * blockDim.x + threadIdx.x) * 2;
  if (e0 + 1 < E) {
    const int2 s2 = *(const int2*)&src[e0];
    const int2 d2 = *(const int2*)&dst[e0];
    const float db = dec_b[0];
    float2 o;
    o.x = p[s2.x] + q[d2.x] + db;
    o.y = p[s2.y] + q[d2.y] + db;
    *(float2*)&out[e0] = o;
  } else if (e0 < E) {
    out[e0] = p[src[e0]] + q[dst[e0]] + dec_b[0];
  }
}

extern "C" void kernel_launch(void* const* d_in, const int* in_sizes, int n_in,
                              void* d_out, int out_size, void* d_ws, size_t ws_size,
                              hipStream_t stream) {
  const float* x     = (const float*)d_in[0];
  const int*   ei    = (const int*)d_in[1];
  const float* ea    = (const float*)d_in[2];
  const float* em_w  = (const float*)d_in[3];
  const float* em_b  = (const float*)d_in[4];
  const float* l1_w  = (const float*)d_in[5];
  const float* l1_b  = (const float*)d_in[6];
  const float* n1_w  = (const float*)d_in[7];
  const float* n1_b  = (const float*)d_in[8];
  const float* l2_w  = (const float*)d_in[9];
  const float* l2_b  = (const float*)d_in[10];
  const float* n2_w  = (const float*)d_in[11];
  const float* n2_b  = (const float*)d_in[12];
  const float* l3_w  = (const float*)d_in[13];
  const float* l3_b  = (const float*)d_in[14];
  const float* n3_w  = (const float*)d_in[15];
  const float* n3_b  = (const float*)d_in[16];
  const float* dec_w = (const float*)d_in[17];
  const float* dec_b = (const float*)d_in[18];
  float* out = (float*)d_out;

  const int N = in_sizes[0];
  const int E = in_sizes[2];
  const int* src = ei;
  const int* dst = ei + E;

  const int NBUCK  = (N + 127) >> 7;        // 391
  const int NBATCH = (E + 2047) >> 11;      // 391
  const int NPAD   = ((N + 15) / 16) * 16;  // multiple of 16
  const int NT16   = NPAD / 16;             // 3125 blocks for layer2

  float* ws       = (float*)d_ws;
  float* consts   = ws;                                   // 1024 f
  ull*   spc      = (ull*)(ws + 1024);                    // NBUCK*CAPC u64
  int2*  spf      = (int2*)(spc + (size_t)NBUCK * CAPC);  // NBUCK*CAPC int2
  unsigned short* h2b = (unsigned short*)(spf + (size_t)NBUCK * CAPC); // NPAD*H
  unsigned short* w2t = h2b + (size_t)NPAD * H;           // H*H bf16
  float* s1       = (float*)(w2t + H * H);
  float* p        = s1 + N;
  float* q        = p + N;
  int*   rowstart = (int*)(q + N) + 512;                  // NBUCK*129

  init_bin<<<17 + NBATCH, 1024, 0, stream>>>(
      src, dst, ea, em_w, em_b, l1_w, l1_b, l2_w, l2_b, n1_b, l3_w, l3_b,
      n2_w, n3_w, n3_b, dec_w, consts, w2t, spc, E, NBUCK);
  fine_scatter<<<NBUCK, 1024, 0, stream>>>(spc, x, consts, spf, rowstart,
                                           s1, N);
  layer2_fused<<<NT16, 512, 0, stream>>>(rowstart, spf, s1, n1_w, n1_b,
                                         consts, w2t, n2_b, h2b, N);
  layer3_dot<<<(N + 3) / 4, 256, 0, stream>>>(rowstart, spf, h2b, consts,
                                              p, q, N);
  final_kernel<<<(E / 2 + 255) / 256, 256, 0, stream>>>(src, dst, p, q, dec_b,
                                                        out, E);
}